// Round 1
// baseline (106.699 us; speedup 1.0000x reference)
//
#include <hip/hip_runtime.h>

#define VV 8
#define JJ 64
#define THR 400.0f
#define ALPHA 0.1f

// ---------------------------------------------------------------------------
// Kernel 1: fold intrinsics into per-(b,v) projection matrices.
//   M[b,v] = K[v] @ [R[b,v] | t[b,v]]   (3x4)
//   N[b,v] = K[v] @ C[b,v]              (3x4)
// Output layout: MN[(b*V+v)*6 + which*3 + r] as float4 rows.
// One thread per row: B*V*6 = 786432 rows.
// ---------------------------------------------------------------------------
__global__ __launch_bounds__(256) void fold_kernel(
    const float* __restrict__ gt_R,   // [B,V,3,3]
    const float* __restrict__ gt_t,   // [B,V,3]
    const float* __restrict__ Kmat,   // [V,3,3]
    const float* __restrict__ cam,    // [B,V,3,4]
    float4* __restrict__ MN,
    int nrows)
{
    const int row = blockIdx.x * 256 + threadIdx.x;
    if (row >= nrows) return;
    const int r = row % 3;
    const int which = (row / 3) & 1;
    const int bv = row / 6;
    const int v = bv & (VV - 1);

    const float* Kv = Kmat + v * 9 + r * 3;
    const float k0 = Kv[0], k1 = Kv[1], k2 = Kv[2];

    float4 o;
    if (which == 0) {
        const float* R = gt_R + (size_t)bv * 9;
        const float* t = gt_t + (size_t)bv * 3;
        o.x = fmaf(k0, R[0], fmaf(k1, R[3], k2 * R[6]));
        o.y = fmaf(k0, R[1], fmaf(k1, R[4], k2 * R[7]));
        o.z = fmaf(k0, R[2], fmaf(k1, R[5], k2 * R[8]));
        o.w = fmaf(k0, t[0], fmaf(k1, t[1], k2 * t[2]));
    } else {
        const float4* C = (const float4*)(cam + (size_t)bv * 12);
        const float4 c0 = C[0], c1 = C[1], c2 = C[2];
        o.x = fmaf(k0, c0.x, fmaf(k1, c1.x, k2 * c2.x));
        o.y = fmaf(k0, c0.y, fmaf(k1, c1.y, k2 * c2.y));
        o.z = fmaf(k0, c0.z, fmaf(k1, c1.z, k2 * c2.z));
        o.w = fmaf(k0, c0.w, fmaf(k1, c1.w, k2 * c2.w));
    }
    MN[row] = o;
}

// ---------------------------------------------------------------------------
// Kernel 2: loss. One wave per batch element, lane = keypoint j.
// No LDS staging, no barriers in the hot path. M/N rows are wave-uniform
// (readfirstlane-forced) -> scalar s_load path, broadcast to lanes.
// ---------------------------------------------------------------------------
__global__ __launch_bounds__(256) void loss_kernel(
    const float* __restrict__ kps_gt,    // [B,J,3]
    const float* __restrict__ kps_pred,  // [B,J,3]
    const float4* __restrict__ MN,       // [B*V*6]
    float* __restrict__ partials)        // [B/4]
{
    __shared__ float s_red[4];
    const int tid = threadIdx.x;
    const int lane = tid & 63;
    const int wave = tid >> 6;
    const int b = __builtin_amdgcn_readfirstlane(blockIdx.x * 4 + wave);

    const float* g = kps_gt + (size_t)b * (JJ * 3) + lane * 3;
    const float X0 = g[0], X1 = g[1], X2 = g[2];
    const float* p = kps_pred + (size_t)b * (JJ * 3) + lane * 3;
    const float P0 = p[0], P1 = p[1], P2 = p[2];

    const float4* mn = MN + (size_t)b * (VV * 6);
    const float c09 = powf(THR, 0.9f);  // compile-time constant

    float acc = 0.0f;
#pragma unroll
    for (int v = 0; v < VV; ++v) {
        const float4 M0 = mn[v * 6 + 0];
        const float4 M1 = mn[v * 6 + 1];
        const float4 M2 = mn[v * 6 + 2];
        const float4 N0 = mn[v * 6 + 3];
        const float4 N1 = mn[v * 6 + 4];
        const float4 N2 = mn[v * 6 + 5];

        const float x0 = fmaf(M0.x, X0, fmaf(M0.y, X1, fmaf(M0.z, X2, M0.w)));
        const float x1 = fmaf(M1.x, X0, fmaf(M1.y, X1, fmaf(M1.z, X2, M1.w)));
        const float x2 = fmaf(M2.x, X0, fmaf(M2.y, X1, fmaf(M2.z, X2, M2.w)));
        const float rg = __builtin_amdgcn_rcpf(x2);
        const float g0 = x0 * rg;
        const float g1 = x1 * rg;

        const float y0 = fmaf(N0.x, P0, fmaf(N0.y, P1, fmaf(N0.z, P2, N0.w)));
        const float y1 = fmaf(N1.x, P0, fmaf(N1.y, P1, fmaf(N1.z, P2, N1.w)));
        const float y2 = fmaf(N2.x, P0, fmaf(N2.y, P1, fmaf(N2.z, P2, N2.w)));
        const float rp = __builtin_amdgcn_rcpf(y2);
        const float q0 = y0 * rp;
        const float q1 = y1 * rp;

        float d0 = g0 - q0; d0 *= d0;
        float d1 = g1 - q1; d1 *= d1;
        // d^0.1 * 400^0.9 via v_log_f32 (log2) + v_exp_f32 (2^x)
        if (d0 > THR) d0 = __builtin_amdgcn_exp2f(ALPHA * __builtin_amdgcn_logf(d0)) * c09;
        if (d1 > THR) d1 = __builtin_amdgcn_exp2f(ALPHA * __builtin_amdgcn_logf(d1)) * c09;
        acc += d0 + d1;
    }

#pragma unroll
    for (int off = 32; off > 0; off >>= 1)
        acc += __shfl_down(acc, off, 64);

    if (lane == 0) s_red[wave] = acc;
    __syncthreads();
    if (tid == 0)
        partials[blockIdx.x] = s_red[0] + s_red[1] + s_red[2] + s_red[3];
}

// ---------------------------------------------------------------------------
// Kernel 3: final reduction of 4096 partials.
// ---------------------------------------------------------------------------
__global__ __launch_bounds__(256) void reduce_kernel(
    const float* __restrict__ partials, float* __restrict__ out,
    float scale, int n)
{
    __shared__ float s_red[4];
    const int tid = threadIdx.x;
    float acc = 0.0f;
    for (int i = tid; i < n; i += 256)
        acc += partials[i];
#pragma unroll
    for (int off = 32; off > 0; off >>= 1)
        acc += __shfl_down(acc, off, 64);
    const int wave = tid >> 6;
    const int lane = tid & 63;
    if (lane == 0) s_red[wave] = acc;
    __syncthreads();
    if (tid == 0)
        out[0] = (s_red[0] + s_red[1] + s_red[2] + s_red[3]) * scale;
}

extern "C" void kernel_launch(void* const* d_in, const int* in_sizes, int n_in,
                              void* d_out, int out_size, void* d_ws, size_t ws_size,
                              hipStream_t stream) {
    const float* kps_gt   = (const float*)d_in[0];
    const float* kps_pred = (const float*)d_in[1];
    const float* gt_R     = (const float*)d_in[2];
    const float* gt_t     = (const float*)d_in[3];
    const float* Kmat     = (const float*)d_in[4];
    const float* cam      = (const float*)d_in[5];
    float* out = (float*)d_out;

    const int B = in_sizes[0] / (JJ * 3);  // 16384
    const float scale = 1.0f / (2.0f * (float)B);

    float4* MN = (float4*)d_ws;                       // B*V*6 float4 = 12.6 MB
    float* partials = (float*)((char*)d_ws + (size_t)B * VV * 6 * sizeof(float4));

    const int nrows = B * VV * 6;                     // 786432
    fold_kernel<<<(nrows + 255) / 256, 256, 0, stream>>>(gt_R, gt_t, Kmat, cam,
                                                         MN, nrows);
    loss_kernel<<<B / 4, 256, 0, stream>>>(kps_gt, kps_pred, MN, partials);
    reduce_kernel<<<1, 256, 0, stream>>>(partials, out, scale, B / 4);
}

// Round 2
// 98.487 us; speedup vs baseline: 1.0834x; 1.0834x over previous
//
#include <hip/hip_runtime.h>

#define VV 8
#define JJ 64
#define THR 400.0f
#define ALPHA 0.1f

// ---------------------------------------------------------------------------
// Fused kernel: fold + loss in one pass.
// Block = 256 threads = 4 waves; each wave owns one batch element b.
// Phase 1: threads 0..191 each compute one projection row
//          (4 b's  x  48 rows: M[v] rows 0-2, N[v] rows 0-2) into LDS.
//          M[b,v] = K[v] @ [R[b,v] | t[b,v]],  N[b,v] = K[v] @ C[b,v]
// Phase 2: wave w processes b = blockIdx.x*4+w, lane = keypoint j.
//          All 48 rows read from LDS at wave-uniform addresses (broadcast).
// One __syncthreads() between phases; per-block partial out.
// ---------------------------------------------------------------------------
__global__ __launch_bounds__(256) void fused_kernel(
    const float* __restrict__ kps_gt,    // [B,J,3]
    const float* __restrict__ kps_pred,  // [B,J,3]
    const float* __restrict__ gt_R,      // [B,V,3,3]
    const float* __restrict__ gt_t,      // [B,V,3]
    const float* __restrict__ Kmat,      // [V,3,3]
    const float* __restrict__ cam,       // [B,V,3,4]
    float* __restrict__ partials)        // [B/4]
{
    __shared__ float4 s_MN[4][48];   // [wave][v*6 + which*3 + r], 3 KB
    __shared__ float s_red[4];

    const int tid = threadIdx.x;

    // ---- phase 1: fold K into per-(b,v) projection rows ----
    if (tid < 192) {
        const int rb = tid / 48;         // which wave's b
        const int rr = tid - rb * 48;    // v*6 + which*3 + r
        const int v  = rr / 6;
        const int w3 = rr - v * 6;
        const int which = w3 / 3;
        const int r  = w3 - which * 3;
        const int b  = blockIdx.x * 4 + rb;
        const size_t bv = (size_t)b * VV + v;

        const float* Kv = Kmat + v * 9 + r * 3;
        const float k0 = Kv[0], k1 = Kv[1], k2 = Kv[2];

        float4 o;
        if (which == 0) {
            const float* R = gt_R + bv * 9;
            const float* t = gt_t + bv * 3;
            o.x = fmaf(k0, R[0], fmaf(k1, R[3], k2 * R[6]));
            o.y = fmaf(k0, R[1], fmaf(k1, R[4], k2 * R[7]));
            o.z = fmaf(k0, R[2], fmaf(k1, R[5], k2 * R[8]));
            o.w = fmaf(k0, t[0], fmaf(k1, t[1], k2 * t[2]));
        } else {
            const float4* C = (const float4*)(cam + bv * 12);
            const float4 c0 = C[0], c1 = C[1], c2 = C[2];
            o.x = fmaf(k0, c0.x, fmaf(k1, c1.x, k2 * c2.x));
            o.y = fmaf(k0, c0.y, fmaf(k1, c1.y, k2 * c2.y));
            o.z = fmaf(k0, c0.z, fmaf(k1, c1.z, k2 * c2.z));
            o.w = fmaf(k0, c0.w, fmaf(k1, c1.w, k2 * c2.w));
        }
        s_MN[rb][rr] = o;
    }
    __syncthreads();

    // ---- phase 2: per-wave loss over one b, lane = keypoint j ----
    const int lane = tid & 63;
    const int wave = tid >> 6;
    const int b = blockIdx.x * 4 + wave;

    const float* g = kps_gt + (size_t)b * (JJ * 3) + lane * 3;
    const float X0 = g[0], X1 = g[1], X2 = g[2];
    const float* p = kps_pred + (size_t)b * (JJ * 3) + lane * 3;
    const float P0 = p[0], P1 = p[1], P2 = p[2];

    const float c09 = powf(THR, 0.9f);  // compile-time constant
    const float4* mn = s_MN[wave];

    float acc = 0.0f;
#pragma unroll
    for (int v = 0; v < VV; ++v) {
        const float4 M0 = mn[v * 6 + 0];
        const float4 M1 = mn[v * 6 + 1];
        const float4 M2 = mn[v * 6 + 2];
        const float4 N0 = mn[v * 6 + 3];
        const float4 N1 = mn[v * 6 + 4];
        const float4 N2 = mn[v * 6 + 5];

        const float x0 = fmaf(M0.x, X0, fmaf(M0.y, X1, fmaf(M0.z, X2, M0.w)));
        const float x1 = fmaf(M1.x, X0, fmaf(M1.y, X1, fmaf(M1.z, X2, M1.w)));
        const float x2 = fmaf(M2.x, X0, fmaf(M2.y, X1, fmaf(M2.z, X2, M2.w)));
        const float rg = __builtin_amdgcn_rcpf(x2);
        const float g0 = x0 * rg;
        const float g1 = x1 * rg;

        const float y0 = fmaf(N0.x, P0, fmaf(N0.y, P1, fmaf(N0.z, P2, N0.w)));
        const float y1 = fmaf(N1.x, P0, fmaf(N1.y, P1, fmaf(N1.z, P2, N1.w)));
        const float y2 = fmaf(N2.x, P0, fmaf(N2.y, P1, fmaf(N2.z, P2, N2.w)));
        const float rp = __builtin_amdgcn_rcpf(y2);
        const float q0 = y0 * rp;
        const float q1 = y1 * rp;

        float d0 = g0 - q0; d0 *= d0;
        float d1 = g1 - q1; d1 *= d1;
        // d^0.1 * 400^0.9 via v_log_f32 (log2) + v_exp_f32 (2^x)
        if (d0 > THR) d0 = __builtin_amdgcn_exp2f(ALPHA * __builtin_amdgcn_logf(d0)) * c09;
        if (d1 > THR) d1 = __builtin_amdgcn_exp2f(ALPHA * __builtin_amdgcn_logf(d1)) * c09;
        acc += d0 + d1;
    }

#pragma unroll
    for (int off = 32; off > 0; off >>= 1)
        acc += __shfl_down(acc, off, 64);

    if (lane == 0) s_red[wave] = acc;
    __syncthreads();
    if (tid == 0)
        partials[blockIdx.x] = s_red[0] + s_red[1] + s_red[2] + s_red[3];
}

// ---------------------------------------------------------------------------
// Final reduction of 4096 partials.
// ---------------------------------------------------------------------------
__global__ __launch_bounds__(256) void reduce_kernel(
    const float* __restrict__ partials, float* __restrict__ out,
    float scale, int n)
{
    __shared__ float s_red[4];
    const int tid = threadIdx.x;
    float acc = 0.0f;
    for (int i = tid; i < n; i += 256)
        acc += partials[i];
#pragma unroll
    for (int off = 32; off > 0; off >>= 1)
        acc += __shfl_down(acc, off, 64);
    const int wave = tid >> 6;
    const int lane = tid & 63;
    if (lane == 0) s_red[wave] = acc;
    __syncthreads();
    if (tid == 0)
        out[0] = (s_red[0] + s_red[1] + s_red[2] + s_red[3]) * scale;
}

extern "C" void kernel_launch(void* const* d_in, const int* in_sizes, int n_in,
                              void* d_out, int out_size, void* d_ws, size_t ws_size,
                              hipStream_t stream) {
    const float* kps_gt   = (const float*)d_in[0];
    const float* kps_pred = (const float*)d_in[1];
    const float* gt_R     = (const float*)d_in[2];
    const float* gt_t     = (const float*)d_in[3];
    const float* Kmat     = (const float*)d_in[4];
    const float* cam      = (const float*)d_in[5];
    float* out = (float*)d_out;

    const int B = in_sizes[0] / (JJ * 3 * 4);  // bytes -> batch; J*3 floats each
    // in_sizes is in bytes? Guard: recompute robustly from float count if not.
    const int B_f = in_sizes[0] / (JJ * 3);    // if in_sizes is float count
    const int Bn = (B_f == 16384 || B == 0) ? B_f : ((B == 16384) ? B : B_f);

    const float scale = 1.0f / (2.0f * (float)Bn);

    float* partials = (float*)d_ws;            // Bn/4 floats

    fused_kernel<<<Bn / 4, 256, 0, stream>>>(kps_gt, kps_pred, gt_R, gt_t,
                                             Kmat, cam, partials);
    reduce_kernel<<<1, 256, 0, stream>>>(partials, out, scale, Bn / 4);
}